// Round 1
// baseline (576.718 us; speedup 1.0000x reference)
//
#include <hip/hip_runtime.h>

typedef unsigned short u16;
typedef __attribute__((ext_vector_type(8))) short short8;
typedef __attribute__((ext_vector_type(4))) float f32x4;
typedef __attribute__((ext_vector_type(4))) unsigned short u16x4;

__device__ __forceinline__ float b2f(u16 u){
  union { float f; unsigned int i; } c; c.i = ((unsigned int)u) << 16; return c.f;
}
__device__ __forceinline__ u16 f2b(float f){
  union { float f; unsigned int i; } c; c.f = f;
  unsigned int i = c.i;
  unsigned int r = (i + 0x7FFFu + ((i >> 16) & 1u)) >> 16;
  return (u16)r;
}

// ---------------------------------------------------------------- convert
__global__ __launch_bounds__(256) void cvt_f32_bf16(const float* __restrict__ in,
                                                    u16* __restrict__ out, int n){
  int i = (blockIdx.x * 256 + threadIdx.x) * 4;
  if (i >= n) return;
  float4 f = *(const float4*)(in + i);
  u16x4 o = { f2b(f.x), f2b(f.y), f2b(f.z), f2b(f.w) };
  *(u16x4*)(out + i) = o;
}

// ---------------------------------------------------------------- GEMM C = A @ B^T (+epilogue)
// A: [M,K] bf16, Bm: [N,K] bf16. 128x128 tile, BK=32, 4 waves (2x2), each 64x64.
enum { EPI_QKV = 0, EPI_WO = 1, EPI_FFN1 = 2, EPI_FFN2 = 3 };

template<int EPI>
__global__ __launch_bounds__(256) void gemm_bt(
    const u16* __restrict__ A, const u16* __restrict__ Bm,
    int M, int N, int K,
    u16* __restrict__ outB,          // QKV: qkv base; FFN1: hidden
    float* __restrict__ outF,        // WO: resid1; FFN2: pre2
    const float* __restrict__ auxF,  // WO: x; FFN1: b1; FFN2: b2
    const u16* __restrict__ auxB)    // FFN2: hb (residual)
{
  __shared__ short Asm[128][40];   // +8 pad: row stride 80B -> 2-way max (free)
  __shared__ short Bsm[128][40];
  const int tid  = threadIdx.x;
  const int lane = tid & 63;
  const int wid  = tid >> 6;
  const int wr = wid >> 1, wc = wid & 1;
  const int fr = lane & 15, fq = lane >> 4;
  const int m0 = blockIdx.y * 128, n0 = blockIdx.x * 128;

  f32x4 acc[4][4];
#pragma unroll
  for (int i = 0; i < 4; i++)
#pragma unroll
    for (int j = 0; j < 4; j++) acc[i][j] = (f32x4){0.f, 0.f, 0.f, 0.f};

  // staging: 128 rows x 32 cols = 512 chunks of 8 bf16; 2 chunks/thread (A and B each)
  const int r0 = tid >> 2,        kc0 = (tid & 3) << 3;
  const int r1 = (tid + 256) >> 2, kc1 = ((tid + 256) & 3) << 3;

  for (int k0 = 0; k0 < K; k0 += 32) {
    short8 a0 = *(const short8*)(A  + (size_t)(m0 + r0) * K + k0 + kc0);
    short8 a1 = *(const short8*)(A  + (size_t)(m0 + r1) * K + k0 + kc1);
    short8 g0 = *(const short8*)(Bm + (size_t)(n0 + r0) * K + k0 + kc0);
    short8 g1 = *(const short8*)(Bm + (size_t)(n0 + r1) * K + k0 + kc1);
    *(short8*)&Asm[r0][kc0] = a0;
    *(short8*)&Asm[r1][kc1] = a1;
    *(short8*)&Bsm[r0][kc0] = g0;
    *(short8*)&Bsm[r1][kc1] = g1;
    __syncthreads();

    short8 af[4], bf[4];
#pragma unroll
    for (int i = 0; i < 4; i++) af[i] = *(const short8*)&Asm[wr*64 + i*16 + fr][fq*8];
#pragma unroll
    for (int j = 0; j < 4; j++) bf[j] = *(const short8*)&Bsm[wc*64 + j*16 + fr][fq*8];
#pragma unroll
    for (int i = 0; i < 4; i++)
#pragma unroll
      for (int j = 0; j < 4; j++)
        acc[i][j] = __builtin_amdgcn_mfma_f32_16x16x32_bf16(af[i], bf[j], acc[i][j], 0, 0, 0);
    __syncthreads();
  }

#pragma unroll
  for (int i = 0; i < 4; i++) {
    const int row0 = m0 + wr*64 + i*16 + fq*4;
#pragma unroll
    for (int j = 0; j < 4; j++) {
      const int col = n0 + wc*64 + j*16 + fr;
#pragma unroll
      for (int r = 0; r < 4; r++) {
        const int row = row0 + r;
        float val = acc[i][j][r];
        if (EPI == EPI_QKV) {
          int t = (col >= 1536) ? 2 : (col >= 768 ? 1 : 0);
          int rem = col - t * 768;
          int h = rem >> 6, e = rem & 63;
          int bb = row >> 11, s = row & 2047;
          size_t idx = (((size_t)(t*48 + bb*12 + h)) * 2048 + s) * 64 + e;
          outB[idx] = f2b(val);
        } else if (EPI == EPI_WO) {
          size_t idx = (size_t)row * 768 + col;
          outF[idx] = val + auxF[idx];
        } else if (EPI == EPI_FFN1) {
          float o = val + auxF[col];
          o = o > 0.f ? o : 0.f;
          outB[(size_t)row * 3072 + col] = f2b(o);
        } else { // EPI_FFN2
          size_t idx = (size_t)row * 768 + col;
          outF[idx] = val + auxF[col] + b2f(auxB[idx]);
        }
      }
    }
  }
}

// ---------------------------------------------------------------- flash attention
// grid (32, 12, 4); 4 waves/block, each wave owns 16 q-rows; K/V tiles of 32 keys.
__global__ __launch_bounds__(256) void flash_attn(
    const u16* __restrict__ q, const u16* __restrict__ kmat, const u16* __restrict__ vmat,
    u16* __restrict__ ctx)
{
  const int tid = threadIdx.x;
  const int lane = tid & 63, wid = tid >> 6;
  const int fr = lane & 15, fq = lane >> 4;
  const int qb = blockIdx.x, h = blockIdx.y, b = blockIdx.z;
  const size_t plane = ((size_t)(b*12 + h)) * 2048 * 64;
  const u16* qp = q + plane;
  const u16* kp = kmat + plane;
  const u16* vp = vmat + plane;

  __shared__ short Ksm[32][72];      // [key][dim], padded
  __shared__ short Vt[64][40];       // [dim][key], padded
  __shared__ short Pm[4][16][40];    // per-wave P tile [qrow][key], padded

  const int qr0 = qb*64 + wid*16;
  const short8 aq0 = *(const short8*)(qp + (size_t)(qr0 + fr)*64 + fq*8);
  const short8 aq1 = *(const short8*)(qp + (size_t)(qr0 + fr)*64 + 32 + fq*8);

  f32x4 o[4];
  float m[4], l[4];
#pragma unroll
  for (int nb = 0; nb < 4; nb++) o[nb] = (f32x4){0.f, 0.f, 0.f, 0.f};
#pragma unroll
  for (int r = 0; r < 4; r++) { m[r] = -1e30f; l[r] = 0.f; }

  const int srow = tid >> 3, skc = (tid & 7) << 3;  // 32 rows x 8 chunks

  for (int kt = 0; kt < 64; ++kt) {
    __syncthreads();
    const size_t gk = ((size_t)(kt*32 + srow)) * 64 + skc;
    short8 kv = *(const short8*)(kp + gk);
    short8 vv = *(const short8*)(vp + gk);
    *(short8*)&Ksm[srow][skc] = kv;
#pragma unroll
    for (int jj = 0; jj < 8; jj++) Vt[skc + jj][srow] = vv[jj];
    __syncthreads();

    // scores: S(16x32) = Q(16x64) @ K_tile^T
    f32x4 s0 = (f32x4){0.f,0.f,0.f,0.f}, s1 = (f32x4){0.f,0.f,0.f,0.f};
    short8 b00 = *(const short8*)&Ksm[fr][fq*8];
    short8 b01 = *(const short8*)&Ksm[fr][32 + fq*8];
    short8 b10 = *(const short8*)&Ksm[16 + fr][fq*8];
    short8 b11 = *(const short8*)&Ksm[16 + fr][32 + fq*8];
    s0 = __builtin_amdgcn_mfma_f32_16x16x32_bf16(aq0, b00, s0, 0, 0, 0);
    s0 = __builtin_amdgcn_mfma_f32_16x16x32_bf16(aq1, b01, s0, 0, 0, 0);
    s1 = __builtin_amdgcn_mfma_f32_16x16x32_bf16(aq0, b10, s1, 0, 0, 0);
    s1 = __builtin_amdgcn_mfma_f32_16x16x32_bf16(aq1, b11, s1, 0, 0, 0);

    float tm[4], p0[4], p1[4], corr[4], rs[4];
#pragma unroll
    for (int r = 0; r < 4; r++) {
      s0[r] *= 0.125f; s1[r] *= 0.125f;
      tm[r] = fmaxf(s0[r], s1[r]);
    }
#pragma unroll
    for (int r = 0; r < 4; r++) {
      tm[r] = fmaxf(tm[r], __shfl_xor(tm[r], 1));
      tm[r] = fmaxf(tm[r], __shfl_xor(tm[r], 2));
      tm[r] = fmaxf(tm[r], __shfl_xor(tm[r], 4));
      tm[r] = fmaxf(tm[r], __shfl_xor(tm[r], 8));
    }
#pragma unroll
    for (int r = 0; r < 4; r++) {
      float nm = fmaxf(m[r], tm[r]);
      corr[r] = __expf(m[r] - nm);
      m[r] = nm;
      p0[r] = __expf(s0[r] - nm);
      p1[r] = __expf(s1[r] - nm);
      rs[r] = p0[r] + p1[r];
    }
#pragma unroll
    for (int r = 0; r < 4; r++) {
      rs[r] += __shfl_xor(rs[r], 1);
      rs[r] += __shfl_xor(rs[r], 2);
      rs[r] += __shfl_xor(rs[r], 4);
      rs[r] += __shfl_xor(rs[r], 8);
    }
#pragma unroll
    for (int r = 0; r < 4; r++) l[r] = l[r] * corr[r] + rs[r];
#pragma unroll
    for (int nb = 0; nb < 4; nb++)
#pragma unroll
      for (int r = 0; r < 4; r++) o[nb][r] *= corr[r];

    // P: C-layout -> LDS -> A-layout
#pragma unroll
    for (int r = 0; r < 4; r++) {
      Pm[wid][fq*4 + r][fr]      = (short)f2b(p0[r]);
      Pm[wid][fq*4 + r][16 + fr] = (short)f2b(p1[r]);
    }
    __syncthreads();
    short8 pa = *(const short8*)&Pm[wid][fr][fq*8];
#pragma unroll
    for (int nb = 0; nb < 4; nb++) {
      short8 bv = *(const short8*)&Vt[nb*16 + fr][fq*8];
      o[nb] = __builtin_amdgcn_mfma_f32_16x16x32_bf16(pa, bv, o[nb], 0, 0, 0);
    }
  }

#pragma unroll
  for (int r = 0; r < 4; r++) {
    const float inv = 1.0f / l[r];
    const int s = qr0 + fq*4 + r;
    u16* cp = ctx + ((size_t)(b*2048 + s)) * 768 + h*64;
#pragma unroll
    for (int nb = 0; nb < 4; nb++)
      cp[nb*16 + fr] = f2b(o[nb][r] * inv);
  }
}

// ---------------------------------------------------------------- layernorm (wave per row)
template<int F32OUT>
__global__ __launch_bounds__(256) void ln_k(const float* __restrict__ in,
    const float* __restrict__ g, const float* __restrict__ be, void* __restrict__ outp)
{
  const int lane = threadIdx.x & 63, wid = threadIdx.x >> 6;
  const int row = blockIdx.x * 4 + wid;
  const float* p = in + (size_t)row * 768;
  float v[12];
  float s = 0.f, s2 = 0.f;
#pragma unroll
  for (int i = 0; i < 12; i++) { v[i] = p[lane + 64*i]; s += v[i]; s2 += v[i]*v[i]; }
#pragma unroll
  for (int msk = 1; msk < 64; msk <<= 1) { s += __shfl_xor(s, msk); s2 += __shfl_xor(s2, msk); }
  const float mu = s * (1.f/768.f);
  const float var = s2 * (1.f/768.f) - mu*mu;
  const float rstd = rsqrtf(var + 1e-5f);
#pragma unroll
  for (int i = 0; i < 12; i++) {
    int c = lane + 64*i;
    float o = (v[i] - mu) * rstd * g[c] + be[c];
    if (F32OUT) ((float*)outp)[(size_t)row*768 + c] = o;
    else        ((u16*)outp)[(size_t)row*768 + c] = f2b(o);
  }
}

// ---------------------------------------------------------------- launch
extern "C" void kernel_launch(void* const* d_in, const int* in_sizes, int n_in,
                              void* d_out, int out_size, void* d_ws, size_t ws_size,
                              hipStream_t stream)
{
  const float* x   = (const float*)d_in[0];
  const float* Wq  = (const float*)d_in[1];
  const float* Wk  = (const float*)d_in[2];
  const float* Wv  = (const float*)d_in[3];
  const float* Wo  = (const float*)d_in[4];
  const float* W1  = (const float*)d_in[5];
  const float* b1  = (const float*)d_in[6];
  const float* W2  = (const float*)d_in[7];
  const float* b2  = (const float*)d_in[8];
  const float* g1  = (const float*)d_in[9];
  const float* be1 = (const float*)d_in[10];
  const float* g2  = (const float*)d_in[11];
  const float* be2 = (const float*)d_in[12];
  float* out = (float*)d_out;

  char* ws = (char*)d_ws;
  u16* xb     = (u16*)(ws + 0);            // 12,582,912 B
  u16* Wqkv_b = (u16*)(ws + 12582912);     //  3,538,944
  u16* Wo_b   = (u16*)(ws + 16121856);     //  1,179,648
  u16* W1_b   = (u16*)(ws + 17301504);     //  4,718,592
  u16* W2_b   = (u16*)(ws + 22020096);     //  4,718,592
  u16* qkv    = (u16*)(ws + 26738688);     // 37,748,736 (q,k,v)
  u16* ctxb   = (u16*)(ws + 64487424);     // 12,582,912
  u16* hidden = (u16*)(ws + 26738688);     // alias qkv+ctx (50,331,648)
  float* resid1 = (float*)(ws + 77070336); // 25,165,824
  u16* hb     = (u16*)(ws + 102236160);    // 12,582,912
  float* pre2 = (float*)(ws + 77070336);   // alias resid1
  // total ws use: 114,819,072 B

  auto cvt = [&](const float* src, u16* dst, int n){
    cvt_f32_bf16<<<dim3((n/4 + 255)/256), dim3(256), 0, stream>>>(src, dst, n);
  };
  cvt(x,  xb, 6291456);
  cvt(Wq, Wqkv_b,            589824);
  cvt(Wk, Wqkv_b +  589824,  589824);
  cvt(Wv, Wqkv_b + 1179648,  589824);
  cvt(Wo, Wo_b, 589824);
  cvt(W1, W1_b, 2359296);
  cvt(W2, W2_b, 2359296);

  // QKV projection: [8192,768] @ [2304,768]^T -> q/k/v bf16 [B,H,S,64]
  gemm_bt<EPI_QKV><<<dim3(2304/128, 8192/128), 256, 0, stream>>>(
      xb, Wqkv_b, 8192, 2304, 768, qkv, nullptr, nullptr, nullptr);

  u16* qb_ = qkv;
  u16* kb_ = qkv + 6291456;
  u16* vb_ = qkv + 12582912;
  flash_attn<<<dim3(32, 12, 4), 256, 0, stream>>>(qb_, kb_, vb_, ctxb);

  // attn_out = ctx @ Wo^T + x  -> resid1 (fp32)
  gemm_bt<EPI_WO><<<dim3(768/128, 8192/128), 256, 0, stream>>>(
      ctxb, Wo_b, 8192, 768, 768, nullptr, resid1, x, nullptr);

  ln_k<0><<<2048, 256, 0, stream>>>(resid1, g1, be1, hb);

  // hidden = relu(hb @ W1^T + b1) bf16
  gemm_bt<EPI_FFN1><<<dim3(3072/128, 8192/128), 256, 0, stream>>>(
      hb, W1_b, 8192, 3072, 768, hidden, nullptr, b1, nullptr);

  // pre2 = hb + hidden @ W2^T + b2 (fp32)
  gemm_bt<EPI_FFN2><<<dim3(768/128, 8192/128), 256, 0, stream>>>(
      hidden, W2_b, 8192, 768, 3072, nullptr, pre2, b2, hb);

  ln_k<1><<<2048, 256, 0, stream>>>(pre2, g2, be2, out);
}

// Round 2
// 440.358 us; speedup vs baseline: 1.3097x; 1.3097x over previous
//
#include <hip/hip_runtime.h>

typedef unsigned short u16;
typedef __attribute__((ext_vector_type(8))) short short8;
typedef __attribute__((ext_vector_type(4))) float f32x4;
typedef __attribute__((ext_vector_type(4))) unsigned short u16x4;

__device__ __forceinline__ float b2f(u16 u){
  union { float f; unsigned int i; } c; c.i = ((unsigned int)u) << 16; return c.f;
}
__device__ __forceinline__ u16 f2b(float f){
  union { float f; unsigned int i; } c; c.f = f;
  unsigned int i = c.i;
  unsigned int r = (i + 0x7FFFu + ((i >> 16) & 1u)) >> 16;
  return (u16)r;
}

// ---------------------------------------------------------------- convert
__global__ __launch_bounds__(256) void cvt_f32_bf16(const float* __restrict__ in,
                                                    u16* __restrict__ out, int n){
  int i = (blockIdx.x * 256 + threadIdx.x) * 4;
  if (i >= n) return;
  float4 f = *(const float4*)(in + i);
  u16x4 o = { f2b(f.x), f2b(f.y), f2b(f.z), f2b(f.w) };
  *(u16x4*)(out + i) = o;
}

// ---------------------------------------------------------------- V transpose: [b,h,s,e] -> [b,h,e,s]
// grid (32, 48): 64-row s-tile per block, one (b,h) plane per blockIdx.y
__global__ __launch_bounds__(256) void transpose_v(const u16* __restrict__ v,
                                                   u16* __restrict__ vt){
  __shared__ short t[64][72];
  const int plane = blockIdx.y;
  const u16* vp = v + (size_t)plane * 2048 * 64;
  u16* vtp = vt + (size_t)plane * 2048 * 64;
  const int s0 = blockIdx.x * 64;
#pragma unroll
  for (int j = 0; j < 2; j++){
    int ch = threadIdx.x + 256*j;
    int r = ch >> 3, c = (ch & 7) << 3;
    short8 val = *(const short8*)(vp + (size_t)(s0 + r)*64 + c);
#pragma unroll
    for (int jj = 0; jj < 8; jj++) t[c + jj][r] = val[jj];
  }
  __syncthreads();
#pragma unroll
  for (int j = 0; j < 2; j++){
    int ch = threadIdx.x + 256*j;
    int r = ch >> 3, c = (ch & 7) << 3;   // r = e-row, c = s-col chunk
    *(short8*)(vtp + (size_t)r*2048 + s0 + c) = *(const short8*)&t[r][c];
  }
}

// ---------------------------------------------------------------- GEMM C = A @ B^T (+epilogue)
enum { EPI_QKV = 0, EPI_WO = 1, EPI_FFN1 = 2, EPI_FFN2 = 3 };

template<int EPI>
__global__ __launch_bounds__(256) void gemm_bt(
    const u16* __restrict__ A, const u16* __restrict__ Bm,
    int M, int N, int K,
    u16* __restrict__ outB,          // QKV: qkv base; FFN1: hidden
    float* __restrict__ outF,        // WO: resid1; FFN2: pre2
    const float* __restrict__ auxF,  // WO: x; FFN1: b1; FFN2: b2
    const u16* __restrict__ auxB)    // FFN2: hb (residual)
{
  __shared__ short Asm[128][40];
  __shared__ short Bsm[128][40];
  const int tid  = threadIdx.x;
  const int lane = tid & 63;
  const int wid  = tid >> 6;
  const int wr = wid >> 1, wc = wid & 1;
  const int fr = lane & 15, fq = lane >> 4;
  const int m0 = blockIdx.y * 128, n0 = blockIdx.x * 128;

  f32x4 acc[4][4];
#pragma unroll
  for (int i = 0; i < 4; i++)
#pragma unroll
    for (int j = 0; j < 4; j++) acc[i][j] = (f32x4){0.f, 0.f, 0.f, 0.f};

  const int r0 = tid >> 2,        kc0 = (tid & 3) << 3;
  const int r1 = (tid + 256) >> 2, kc1 = ((tid + 256) & 3) << 3;

  for (int k0 = 0; k0 < K; k0 += 32) {
    short8 a0 = *(const short8*)(A  + (size_t)(m0 + r0) * K + k0 + kc0);
    short8 a1 = *(const short8*)(A  + (size_t)(m0 + r1) * K + k0 + kc1);
    short8 g0 = *(const short8*)(Bm + (size_t)(n0 + r0) * K + k0 + kc0);
    short8 g1 = *(const short8*)(Bm + (size_t)(n0 + r1) * K + k0 + kc1);
    *(short8*)&Asm[r0][kc0] = a0;
    *(short8*)&Asm[r1][kc1] = a1;
    *(short8*)&Bsm[r0][kc0] = g0;
    *(short8*)&Bsm[r1][kc1] = g1;
    __syncthreads();

    short8 af[4], bf[4];
#pragma unroll
    for (int i = 0; i < 4; i++) af[i] = *(const short8*)&Asm[wr*64 + i*16 + fr][fq*8];
#pragma unroll
    for (int j = 0; j < 4; j++) bf[j] = *(const short8*)&Bsm[wc*64 + j*16 + fr][fq*8];
#pragma unroll
    for (int i = 0; i < 4; i++)
#pragma unroll
      for (int j = 0; j < 4; j++)
        acc[i][j] = __builtin_amdgcn_mfma_f32_16x16x32_bf16(af[i], bf[j], acc[i][j], 0, 0, 0);
    __syncthreads();
  }

#pragma unroll
  for (int i = 0; i < 4; i++) {
    const int row0 = m0 + wr*64 + i*16 + fq*4;
#pragma unroll
    for (int j = 0; j < 4; j++) {
      const int col = n0 + wc*64 + j*16 + fr;
#pragma unroll
      for (int r = 0; r < 4; r++) {
        const int row = row0 + r;
        float val = acc[i][j][r];
        if (EPI == EPI_QKV) {
          int t = (col >= 1536) ? 2 : (col >= 768 ? 1 : 0);
          int rem = col - t * 768;
          int h = rem >> 6, e = rem & 63;
          int bb = row >> 11, s = row & 2047;
          size_t idx = (((size_t)(t*48 + bb*12 + h)) * 2048 + s) * 64 + e;
          outB[idx] = f2b(val);
        } else if (EPI == EPI_WO) {
          size_t idx = (size_t)row * 768 + col;
          outF[idx] = val + auxF[idx];
        } else if (EPI == EPI_FFN1) {
          float o = val + auxF[col];
          o = o > 0.f ? o : 0.f;
          outB[(size_t)row * 3072 + col] = f2b(o);
        } else { // EPI_FFN2
          size_t idx = (size_t)row * 768 + col;
          outF[idx] = val + auxF[col] + b2f(auxB[idx]);
        }
      }
    }
  }
}

// ---------------------------------------------------------------- flash attention
// 1D grid 1536 (XCD-swizzled). 4 waves/block, each wave 16 q-rows; KVBLK=64.
__global__ __launch_bounds__(256) void flash_attn(
    const u16* __restrict__ q, const u16* __restrict__ kmat, const u16* __restrict__ vtmat,
    u16* __restrict__ ctx)
{
  const int tid = threadIdx.x;
  const int lane = tid & 63, wid = tid >> 6;
  const int fr = lane & 15, fq = lane >> 4;
  // bijective XCD swizzle: 1536 = 8 * 192 -> each XCD gets 192 consecutive wgids (6 planes)
  const int orig = blockIdx.x;
  const int wg = (orig & 7) * 192 + (orig >> 3);
  const int qb = wg & 31;
  const int ph = wg >> 5;                 // plane index 0..47 = b*12+h
  const size_t plane = (size_t)ph * 2048 * 64;
  const u16* qp  = q + plane;
  const u16* kp  = kmat + plane;
  const u16* vtp = vtmat + plane;         // [64 dims][2048 keys]

  __shared__ short Ksm[64][72];           // [key][dim]
  __shared__ short Vt[64][72];            // [dim][key]
  __shared__ short Pm[4][16][72];         // per-wave P [qrow][key]

  const int qr0 = qb*64 + wid*16;
  const short8 aq0 = *(const short8*)(qp + (size_t)(qr0 + fr)*64 + fq*8);
  const short8 aq1 = *(const short8*)(qp + (size_t)(qr0 + fr)*64 + 32 + fq*8);

  f32x4 o[4];
  float m[4], l[4];
#pragma unroll
  for (int nb = 0; nb < 4; nb++) o[nb] = (f32x4){0.f, 0.f, 0.f, 0.f};
#pragma unroll
  for (int r = 0; r < 4; r++) { m[r] = -1e30f; l[r] = 0.f; }

  for (int kt = 0; kt < 32; ++kt) {
    __syncthreads();
#pragma unroll
    for (int j = 0; j < 2; j++) {
      int ch = tid + 256*j;
      int r = ch >> 3, c = (ch & 7) << 3;
      *(short8*)&Ksm[r][c] = *(const short8*)(kp + (size_t)(kt*64 + r)*64 + c);
      *(short8*)&Vt[r][c]  = *(const short8*)(vtp + (size_t)r*2048 + kt*64 + c);
    }
    __syncthreads();

    // S(16x64) = Q(16x64) @ Ktile^T
    f32x4 s[4];
#pragma unroll
    for (int nb = 0; nb < 4; nb++) {
      s[nb] = (f32x4){0.f,0.f,0.f,0.f};
      short8 b0 = *(const short8*)&Ksm[nb*16 + fr][fq*8];
      short8 b1 = *(const short8*)&Ksm[nb*16 + fr][32 + fq*8];
      s[nb] = __builtin_amdgcn_mfma_f32_16x16x32_bf16(aq0, b0, s[nb], 0, 0, 0);
      s[nb] = __builtin_amdgcn_mfma_f32_16x16x32_bf16(aq1, b1, s[nb], 0, 0, 0);
    }

    float tm[4], corr[4], rs[4];
    float p[4][4];
#pragma unroll
    for (int nb = 0; nb < 4; nb++)
#pragma unroll
      for (int r = 0; r < 4; r++) s[nb][r] *= 0.125f;
#pragma unroll
    for (int r = 0; r < 4; r++) {
      tm[r] = fmaxf(fmaxf(s[0][r], s[1][r]), fmaxf(s[2][r], s[3][r]));
      tm[r] = fmaxf(tm[r], __shfl_xor(tm[r], 1));
      tm[r] = fmaxf(tm[r], __shfl_xor(tm[r], 2));
      tm[r] = fmaxf(tm[r], __shfl_xor(tm[r], 4));
      tm[r] = fmaxf(tm[r], __shfl_xor(tm[r], 8));
    }
#pragma unroll
    for (int r = 0; r < 4; r++) {
      float nm = fmaxf(m[r], tm[r]);
      corr[r] = __expf(m[r] - nm);
      m[r] = nm;
      rs[r] = 0.f;
#pragma unroll
      for (int nb = 0; nb < 4; nb++) {
        p[nb][r] = __expf(s[nb][r] - nm);
        rs[r] += p[nb][r];
      }
    }
#pragma unroll
    for (int r = 0; r < 4; r++) {
      rs[r] += __shfl_xor(rs[r], 1);
      rs[r] += __shfl_xor(rs[r], 2);
      rs[r] += __shfl_xor(rs[r], 4);
      rs[r] += __shfl_xor(rs[r], 8);
      l[r] = l[r] * corr[r] + rs[r];
    }
#pragma unroll
    for (int nb = 0; nb < 4; nb++)
#pragma unroll
      for (int r = 0; r < 4; r++) o[nb][r] *= corr[r];

    // P: C-layout -> LDS (wave-local, no barrier) -> A-layout
#pragma unroll
    for (int nb = 0; nb < 4; nb++)
#pragma unroll
      for (int r = 0; r < 4; r++)
        Pm[wid][fq*4 + r][nb*16 + fr] = (short)f2b(p[nb][r]);
    short8 pa0 = *(const short8*)&Pm[wid][fr][fq*8];
    short8 pa1 = *(const short8*)&Pm[wid][fr][32 + fq*8];
#pragma unroll
    for (int nb = 0; nb < 4; nb++) {
      short8 bv0 = *(const short8*)&Vt[nb*16 + fr][fq*8];
      short8 bv1 = *(const short8*)&Vt[nb*16 + fr][32 + fq*8];
      o[nb] = __builtin_amdgcn_mfma_f32_16x16x32_bf16(pa0, bv0, o[nb], 0, 0, 0);
      o[nb] = __builtin_amdgcn_mfma_f32_16x16x32_bf16(pa1, bv1, o[nb], 0, 0, 0);
    }
  }

#pragma unroll
  for (int r = 0; r < 4; r++) {
    const float inv = 1.0f / l[r];
    const int s = qr0 + fq*4 + r;
    u16* cp = ctx + ((size_t)((ph/12)*2048 + s)) * 768 + (ph%12)*64;
#pragma unroll
    for (int nb = 0; nb < 4; nb++)
      cp[nb*16 + fr] = f2b(o[nb][r] * inv);
  }
}

// ---------------------------------------------------------------- layernorm (wave per row)
template<int F32OUT>
__global__ __launch_bounds__(256) void ln_k(const float* __restrict__ in,
    const float* __restrict__ g, const float* __restrict__ be, void* __restrict__ outp)
{
  const int lane = threadIdx.x & 63, wid = threadIdx.x >> 6;
  const int row = blockIdx.x * 4 + wid;
  const float* p = in + (size_t)row * 768;
  float v[12];
  float s = 0.f, s2 = 0.f;
#pragma unroll
  for (int i = 0; i < 12; i++) { v[i] = p[lane + 64*i]; s += v[i]; s2 += v[i]*v[i]; }
#pragma unroll
  for (int msk = 1; msk < 64; msk <<= 1) { s += __shfl_xor(s, msk); s2 += __shfl_xor(s2, msk); }
  const float mu = s * (1.f/768.f);
  const float var = s2 * (1.f/768.f) - mu*mu;
  const float rstd = rsqrtf(var + 1e-5f);
#pragma unroll
  for (int i = 0; i < 12; i++) {
    int c = lane + 64*i;
    float o = (v[i] - mu) * rstd * g[c] + be[c];
    if (F32OUT) ((float*)outp)[(size_t)row*768 + c] = o;
    else        ((u16*)outp)[(size_t)row*768 + c] = f2b(o);
  }
}

// ---------------------------------------------------------------- launch
extern "C" void kernel_launch(void* const* d_in, const int* in_sizes, int n_in,
                              void* d_out, int out_size, void* d_ws, size_t ws_size,
                              hipStream_t stream)
{
  const float* x   = (const float*)d_in[0];
  const float* Wq  = (const float*)d_in[1];
  const float* Wk  = (const float*)d_in[2];
  const float* Wv  = (const float*)d_in[3];
  const float* Wo  = (const float*)d_in[4];
  const float* W1  = (const float*)d_in[5];
  const float* b1  = (const float*)d_in[6];
  const float* W2  = (const float*)d_in[7];
  const float* b2  = (const float*)d_in[8];
  const float* g1  = (const float*)d_in[9];
  const float* be1 = (const float*)d_in[10];
  const float* g2  = (const float*)d_in[11];
  const float* be2 = (const float*)d_in[12];
  float* out = (float*)d_out;

  char* ws = (char*)d_ws;
  u16* xb     = (u16*)(ws + 0);            // 12,582,912 B
  u16* Wqkv_b = (u16*)(ws + 12582912);     //  3,538,944
  u16* Wo_b   = (u16*)(ws + 16121856);     //  1,179,648
  u16* W1_b   = (u16*)(ws + 17301504);     //  4,718,592
  u16* W2_b   = (u16*)(ws + 22020096);     //  4,718,592
  u16* qkv    = (u16*)(ws + 26738688);     // 37,748,736 (q,k,v)
  u16* ctxb   = (u16*)(ws + 64487424);     // 12,582,912
  u16* hidden = (u16*)(ws + 26738688);     // alias qkv+ctx (50,331,648)
  float* resid1 = (float*)(ws + 77070336); // 25,165,824
  u16* vt     = (u16*)(ws + 77070336);     // 12,582,912 — aliases resid1 (dead until WO gemm)
  u16* hb     = (u16*)(ws + 102236160);    // 12,582,912
  float* pre2 = (float*)(ws + 77070336);   // alias resid1
  // total ws use: 114,819,072 B

  auto cvt = [&](const float* src, u16* dst, int n){
    cvt_f32_bf16<<<dim3((n/4 + 255)/256), dim3(256), 0, stream>>>(src, dst, n);
  };
  cvt(x,  xb, 6291456);
  cvt(Wq, Wqkv_b,            589824);
  cvt(Wk, Wqkv_b +  589824,  589824);
  cvt(Wv, Wqkv_b + 1179648,  589824);
  cvt(Wo, Wo_b, 589824);
  cvt(W1, W1_b, 2359296);
  cvt(W2, W2_b, 2359296);

  // QKV projection: [8192,768] @ [2304,768]^T -> q/k/v bf16 [B,H,S,64]
  gemm_bt<EPI_QKV><<<dim3(2304/128, 8192/128), 256, 0, stream>>>(
      xb, Wqkv_b, 8192, 2304, 768, qkv, nullptr, nullptr, nullptr);

  u16* qb_ = qkv;
  u16* kb_ = qkv + 6291456;
  u16* vb_ = qkv + 12582912;

  // V -> V^T [b,h,e,s]
  transpose_v<<<dim3(32, 48), 256, 0, stream>>>(vb_, vt);

  flash_attn<<<dim3(1536), 256, 0, stream>>>(qb_, kb_, vt, ctxb);

  // attn_out = ctx @ Wo^T + x  -> resid1 (fp32)
  gemm_bt<EPI_WO><<<dim3(768/128, 8192/128), 256, 0, stream>>>(
      ctxb, Wo_b, 8192, 768, 768, nullptr, resid1, x, nullptr);

  ln_k<0><<<2048, 256, 0, stream>>>(resid1, g1, be1, hb);

  // hidden = relu(hb @ W1^T + b1) bf16
  gemm_bt<EPI_FFN1><<<dim3(3072/128, 8192/128), 256, 0, stream>>>(
      hb, W1_b, 8192, 3072, 768, hidden, nullptr, b1, nullptr);

  // pre2 = hb + hidden @ W2^T + b2 (fp32)
  gemm_bt<EPI_FFN2><<<dim3(768/128, 8192/128), 256, 0, stream>>>(
      hidden, W2_b, 8192, 768, 3072, nullptr, pre2, b2, hb);

  ln_k<1><<<2048, 256, 0, stream>>>(pre2, g2, be2, out);
}

// Round 3
// 379.103 us; speedup vs baseline: 1.5213x; 1.1616x over previous
//
#include <hip/hip_runtime.h>

typedef unsigned short u16;
typedef unsigned int u32;
typedef __attribute__((ext_vector_type(8))) short short8;
typedef __attribute__((ext_vector_type(4))) float f32x4;
typedef __attribute__((ext_vector_type(4))) unsigned short u16x4;

__device__ __forceinline__ float b2f(u16 u){
  union { float f; unsigned int i; } c; c.i = ((unsigned int)u) << 16; return c.f;
}
__device__ __forceinline__ u16 f2b(float f){
  union { float f; unsigned int i; } c; c.f = f;
  unsigned int i = c.i;
  unsigned int r = (i + 0x7FFFu + ((i >> 16) & 1u)) >> 16;
  return (u16)r;
}

#if __has_builtin(__builtin_amdgcn_exp2f)
#define EXP2(x) __builtin_amdgcn_exp2f(x)
#else
#define EXP2(x) exp2f(x)
#endif

#define GLD16(gp, lp) __builtin_amdgcn_global_load_lds( \
    (const __attribute__((address_space(1))) void*)(gp), \
    (__attribute__((address_space(3))) void*)(lp), 16, 0, 0)

__device__ __forceinline__ u32 pkbf(float lo, float hi){
  u32 r;
  asm volatile("v_cvt_pk_bf16_f32 %0, %1, %2" : "=v"(r) : "v"(lo), "v"(hi));
  return r;
}

// ---------------------------------------------------------------- convert
__global__ __launch_bounds__(256) void cvt_f32_bf16(const float* __restrict__ in,
                                                    u16* __restrict__ out, int n){
  int i = (blockIdx.x * 256 + threadIdx.x) * 4;
  if (i >= n) return;
  float4 f = *(const float4*)(in + i);
  u16x4 o = { f2b(f.x), f2b(f.y), f2b(f.z), f2b(f.w) };
  *(u16x4*)(out + i) = o;
}

// ---------------------------------------------------------------- V transpose: [b,h,s,e] -> [b,h,e,s]
__global__ __launch_bounds__(256) void transpose_v(const u16* __restrict__ v,
                                                   u16* __restrict__ vt){
  __shared__ short t[64][72];
  const int plane = blockIdx.y;
  const u16* vp = v + (size_t)plane * 2048 * 64;
  u16* vtp = vt + (size_t)plane * 2048 * 64;
  const int s0 = blockIdx.x * 64;
#pragma unroll
  for (int j = 0; j < 2; j++){
    int ch = threadIdx.x + 256*j;
    int r = ch >> 3, c = (ch & 7) << 3;
    short8 val = *(const short8*)(vp + (size_t)(s0 + r)*64 + c);
#pragma unroll
    for (int jj = 0; jj < 8; jj++) t[c + jj][r] = val[jj];
  }
  __syncthreads();
#pragma unroll
  for (int j = 0; j < 2; j++){
    int ch = threadIdx.x + 256*j;
    int r = ch >> 3, c = (ch & 7) << 3;
    *(short8*)(vtp + (size_t)r*2048 + s0 + c) = *(const short8*)&t[r][c];
  }
}

// ---------------------------------------------------------------- GEMM C = A @ B^T (+epilogue)
enum { EPI_QKV = 0, EPI_WO = 1, EPI_FFN1 = 2, EPI_FFN2 = 3 };

template<int EPI>
__global__ __launch_bounds__(256) void gemm_bt(
    const u16* __restrict__ A, const u16* __restrict__ Bm,
    int M, int N, int K,
    u16* __restrict__ outB, float* __restrict__ outF,
    const float* __restrict__ auxF, const u16* __restrict__ auxB)
{
  __shared__ __align__(16) short Asm[128][32];   // linear: global_load_lds needs contiguity
  __shared__ __align__(16) short Bsm[128][32];
  const int tid  = threadIdx.x;
  const int lane = tid & 63;
  const int wid  = tid >> 6;
  const int wr = wid >> 1, wc = wid & 1;
  const int fr = lane & 15, fq = lane >> 4;
  const int m0 = blockIdx.y * 128, n0 = blockIdx.x * 128;

  f32x4 acc[4][4];
#pragma unroll
  for (int i = 0; i < 4; i++)
#pragma unroll
    for (int j = 0; j < 4; j++) acc[i][j] = (f32x4){0.f, 0.f, 0.f, 0.f};

  const int lrow = lane >> 2;             // 0..15
  const int lcol = (lane & 3) << 3;       // u16 offset 0..24

  for (int k0 = 0; k0 < K; k0 += 32) {
    // 4 waves x (2 A + 2 B) global_load_lds_dwordx4, 1KB each
    const u16* ga = A  + (size_t)(m0 + wid*32 + lrow) * K + k0 + lcol;
    const u16* gb = Bm + (size_t)(n0 + wid*32 + lrow) * K + k0 + lcol;
    GLD16(ga,                 &Asm[wid*32][0]);
    GLD16(ga + (size_t)16*K,  &Asm[wid*32 + 16][0]);
    GLD16(gb,                 &Bsm[wid*32][0]);
    GLD16(gb + (size_t)16*K,  &Bsm[wid*32 + 16][0]);
    __syncthreads();

    short8 af[4], bf[4];
#pragma unroll
    for (int i = 0; i < 4; i++) af[i] = *(const short8*)&Asm[wr*64 + i*16 + fr][fq*8];
#pragma unroll
    for (int j = 0; j < 4; j++) bf[j] = *(const short8*)&Bsm[wc*64 + j*16 + fr][fq*8];
#pragma unroll
    for (int i = 0; i < 4; i++)
#pragma unroll
      for (int j = 0; j < 4; j++)
        acc[i][j] = __builtin_amdgcn_mfma_f32_16x16x32_bf16(af[i], bf[j], acc[i][j], 0, 0, 0);
    __syncthreads();
  }

  const float KSCALE = 0.125f * 1.44269504088896340736f;  // fold score scale+log2e into K
#pragma unroll
  for (int i = 0; i < 4; i++) {
    const int row0 = m0 + wr*64 + i*16 + fq*4;
#pragma unroll
    for (int j = 0; j < 4; j++) {
      const int col = n0 + wc*64 + j*16 + fr;
#pragma unroll
      for (int r = 0; r < 4; r++) {
        const int row = row0 + r;
        float val = acc[i][j][r];
        if (EPI == EPI_QKV) {
          int t = (col >= 1536) ? 2 : (col >= 768 ? 1 : 0);
          int rem = col - t * 768;
          int h = rem >> 6, e = rem & 63;
          int bb = row >> 11, s = row & 2047;
          size_t idx = (((size_t)(t*48 + bb*12 + h)) * 2048 + s) * 64 + e;
          if (t == 1) val *= KSCALE;
          outB[idx] = f2b(val);
        } else if (EPI == EPI_WO) {
          size_t idx = (size_t)row * 768 + col;
          outF[idx] = val + auxF[idx];
        } else if (EPI == EPI_FFN1) {
          float o = val + auxF[col];
          o = o > 0.f ? o : 0.f;
          outB[(size_t)row * 3072 + col] = f2b(o);
        } else { // EPI_FFN2
          size_t idx = (size_t)row * 768 + col;
          outF[idx] = val + auxF[col] + b2f(auxB[idx]);
        }
      }
    }
  }
}

// ---------------------------------------------------------------- flash attention
// Swapped-QK^T design: S^T = mfma(K,Q) -> lane owns row q=lane&15, kk over (fq,reg).
// In-register softmax + in-register P redistribution (cvt_pk + shfl_xor 16/32).
__device__ __forceinline__ short8 build_pfrag(const float* p, int fq){
  // p[0..3]: kk = 4fq+r ; p[4..7]: kk = 16+4fq+r  (one 32-wide kk half)
  u32 w0 = pkbf(p[0], p[1]);   // word W=2fq
  u32 w1 = pkbf(p[2], p[3]);   // W=2fq+1
  u32 w2 = pkbf(p[4], p[5]);   // W=8+2fq
  u32 w3 = pkbf(p[6], p[7]);   // W=8+2fq+1
  u32 a0 = (u32)__shfl_xor((int)w0, 16);
  u32 a1 = (u32)__shfl_xor((int)w1, 16);
  u32 a2 = (u32)__shfl_xor((int)w2, 16);
  u32 a3 = (u32)__shfl_xor((int)w3, 16);
  const bool odd = (fq & 1) != 0, hi = fq >= 2;
  // sorted quads: L = lower 4 words this half-pair owns, H = upper 4
  u32 L0 = odd ? a0 : w0, L1 = odd ? a1 : w1, L2 = odd ? w0 : a0, L3 = odd ? w1 : a1;
  u32 H0 = odd ? a2 : w2, H1 = odd ? a3 : w3, H2 = odd ? w2 : a2, H3 = odd ? w3 : a3;
  // xor-32 exchange: fq<2 present H (needed by fq+2), fq>=2 present L (needed by fq-2)
  u32 s0 = hi ? L0 : H0, s1 = hi ? L1 : H1, s2 = hi ? L2 : H2, s3 = hi ? L3 : H3;
  u32 b0 = (u32)__shfl_xor((int)s0, 32);
  u32 b1 = (u32)__shfl_xor((int)s1, 32);
  u32 b2 = (u32)__shfl_xor((int)s2, 32);
  u32 b3 = (u32)__shfl_xor((int)s3, 32);
  u32 F0 = (fq == 0) ? L0 : (fq == 3) ? H0 : b0;
  u32 F1 = (fq == 0) ? L1 : (fq == 3) ? H1 : b1;
  u32 F2 = (fq == 0) ? L2 : (fq == 3) ? H2 : b2;
  u32 F3 = (fq == 0) ? L3 : (fq == 3) ? H3 : b3;
  union { u32 u[4]; short8 s8; } cv;
  cv.u[0] = F0; cv.u[1] = F1; cv.u[2] = F2; cv.u[3] = F3;
  return cv.s8;
}

__global__ __launch_bounds__(256) void flash_attn(
    const u16* __restrict__ q, const u16* __restrict__ kmat, const u16* __restrict__ vtmat,
    u16* __restrict__ ctx)
{
  const int tid = threadIdx.x;
  const int lane = tid & 63, wid = tid >> 6;
  const int fr = lane & 15, fq = lane >> 4;
  const int orig = blockIdx.x;
  const int wg = (orig & 7) * 192 + (orig >> 3);   // 1536 = 8*192, bijective
  const int qb = wg & 31;
  const int ph = wg >> 5;
  const size_t plane = (size_t)ph * 2048 * 64;
  const u16* qp  = q + plane;
  const u16* kp  = kmat + plane;
  const u16* vtp = vtmat + plane;

  __shared__ short Ksm[64][72];
  __shared__ short Vt[64][72];

  const int qr0 = qb*64 + wid*16;
  const short8 aq0 = *(const short8*)(qp + (size_t)(qr0 + fr)*64 + fq*8);
  const short8 aq1 = *(const short8*)(qp + (size_t)(qr0 + fr)*64 + 32 + fq*8);

  f32x4 o[4];
#pragma unroll
  for (int eb = 0; eb < 4; eb++) o[eb] = (f32x4){0.f, 0.f, 0.f, 0.f};
  float m = -1e30f, l = 0.f;

  const f32x4 zero = (f32x4){0.f, 0.f, 0.f, 0.f};

  for (int kt = 0; kt < 32; ++kt) {
    __syncthreads();
#pragma unroll
    for (int j = 0; j < 2; j++) {
      int ch = tid + 256*j;
      int r = ch >> 3, c = (ch & 7) << 3;
      *(short8*)&Ksm[r][c] = *(const short8*)(kp + (size_t)(kt*64 + r)*64 + c);
      *(short8*)&Vt[r][c]  = *(const short8*)(vtp + (size_t)r*2048 + kt*64 + c);
    }
    __syncthreads();

    // S^T(64x16) = Ktile(64x64d) x Q^T : lane -> q=fr, kk = nb*16 + 4*fq + r
    f32x4 st[4];
#pragma unroll
    for (int nb = 0; nb < 4; nb++) {
      short8 kf0 = *(const short8*)&Ksm[nb*16 + fr][fq*8];
      short8 kf1 = *(const short8*)&Ksm[nb*16 + fr][32 + fq*8];
      st[nb] = __builtin_amdgcn_mfma_f32_16x16x32_bf16(kf0, aq0, zero, 0, 0, 0);
      st[nb] = __builtin_amdgcn_mfma_f32_16x16x32_bf16(kf1, aq1, st[nb], 0, 0, 0);
    }
    // scores already in log2-units (K was pre-scaled by 0.125*log2e)

    float lm = st[0][0];
#pragma unroll
    for (int nb = 0; nb < 4; nb++)
#pragma unroll
      for (int r = 0; r < 4; r++) lm = fmaxf(lm, st[nb][r]);
    lm = fmaxf(lm, __shfl_xor(lm, 16));
    lm = fmaxf(lm, __shfl_xor(lm, 32));

    float nm = fmaxf(m, lm);
    float corr = EXP2(m - nm);
    m = nm;

    float p[16];
    float ls = 0.f;
#pragma unroll
    for (int nb = 0; nb < 4; nb++)
#pragma unroll
      for (int r = 0; r < 4; r++) {
        float pv = EXP2(st[nb][r] - nm);
        p[nb*4 + r] = pv;
        ls += pv;
      }
    ls += __shfl_xor(ls, 16);
    ls += __shfl_xor(ls, 32);
    l = l * corr + ls;

#pragma unroll
    for (int eb = 0; eb < 4; eb++)
#pragma unroll
      for (int r = 0; r < 4; r++) o[eb][r] *= corr;

    short8 pf0 = build_pfrag(&p[0], fq);   // kk 0..31
    short8 pf1 = build_pfrag(&p[8], fq);   // kk 32..63

    // O^T(64e x 16q) += V^T(64e x 64kk) x P(64kk x 16q)
#pragma unroll
    for (int eb = 0; eb < 4; eb++) {
      short8 vf0 = *(const short8*)&Vt[eb*16 + fr][fq*8];
      short8 vf1 = *(const short8*)&Vt[eb*16 + fr][32 + fq*8];
      o[eb] = __builtin_amdgcn_mfma_f32_16x16x32_bf16(vf0, pf0, o[eb], 0, 0, 0);
      o[eb] = __builtin_amdgcn_mfma_f32_16x16x32_bf16(vf1, pf1, o[eb], 0, 0, 0);
    }
  }

  const float inv = 1.0f / l;
  const int s = qr0 + fr;
  u16* cp = ctx + ((size_t)((ph/12)*2048 + s)) * 768 + (ph%12)*64;
#pragma unroll
  for (int eb = 0; eb < 4; eb++) {
    u16x4 w = { f2b(o[eb][0]*inv), f2b(o[eb][1]*inv), f2b(o[eb][2]*inv), f2b(o[eb][3]*inv) };
    *(u16x4*)(cp + eb*16 + fq*4) = w;   // e = eb*16 + 4*fq + r
  }
}

// ---------------------------------------------------------------- layernorm (wave per row)
template<int F32OUT>
__global__ __launch_bounds__(256) void ln_k(const float* __restrict__ in,
    const float* __restrict__ g, const float* __restrict__ be, void* __restrict__ outp)
{
  const int lane = threadIdx.x & 63, wid = threadIdx.x >> 6;
  const int row = blockIdx.x * 4 + wid;
  const float* p = in + (size_t)row * 768;
  float v[12];
  float s = 0.f, s2 = 0.f;
#pragma unroll
  for (int i = 0; i < 12; i++) { v[i] = p[lane + 64*i]; s += v[i]; s2 += v[i]*v[i]; }
#pragma unroll
  for (int msk = 1; msk < 64; msk <<= 1) { s += __shfl_xor(s, msk); s2 += __shfl_xor(s2, msk); }
  const float mu = s * (1.f/768.f);
  const float var = s2 * (1.f/768.f) - mu*mu;
  const float rstd = rsqrtf(var + 1e-5f);
#pragma unroll
  for (int i = 0; i < 12; i++) {
    int c = lane + 64*i;
    float o = (v[i] - mu) * rstd * g[c] + be[c];
    if (F32OUT) ((float*)outp)[(size_t)row*768 + c] = o;
    else        ((u16*)outp)[(size_t)row*768 + c] = f2b(o);
  }
}

// ---------------------------------------------------------------- launch
extern "C" void kernel_launch(void* const* d_in, const int* in_sizes, int n_in,
                              void* d_out, int out_size, void* d_ws, size_t ws_size,
                              hipStream_t stream)
{
  const float* x   = (const float*)d_in[0];
  const float* Wq  = (const float*)d_in[1];
  const float* Wk  = (const float*)d_in[2];
  const float* Wv  = (const float*)d_in[3];
  const float* Wo  = (const float*)d_in[4];
  const float* W1  = (const float*)d_in[5];
  const float* b1  = (const float*)d_in[6];
  const float* W2  = (const float*)d_in[7];
  const float* b2  = (const float*)d_in[8];
  const float* g1  = (const float*)d_in[9];
  const float* be1 = (const float*)d_in[10];
  const float* g2  = (const float*)d_in[11];
  const float* be2 = (const float*)d_in[12];
  float* out = (float*)d_out;

  char* ws = (char*)d_ws;
  u16* xb     = (u16*)(ws + 0);
  u16* Wqkv_b = (u16*)(ws + 12582912);
  u16* Wo_b   = (u16*)(ws + 16121856);
  u16* W1_b   = (u16*)(ws + 17301504);
  u16* W2_b   = (u16*)(ws + 22020096);
  u16* qkv    = (u16*)(ws + 26738688);
  u16* ctxb   = (u16*)(ws + 64487424);
  u16* hidden = (u16*)(ws + 26738688);     // alias qkv+ctx
  float* resid1 = (float*)(ws + 77070336);
  u16* vt     = (u16*)(ws + 77070336);     // aliases resid1 (dead until WO gemm)
  u16* hb     = (u16*)(ws + 102236160);
  float* pre2 = (float*)(ws + 77070336);

  auto cvt = [&](const float* src, u16* dst, int n){
    cvt_f32_bf16<<<dim3((n/4 + 255)/256), dim3(256), 0, stream>>>(src, dst, n);
  };
  cvt(x,  xb, 6291456);
  cvt(Wq, Wqkv_b,            589824);
  cvt(Wk, Wqkv_b +  589824,  589824);
  cvt(Wv, Wqkv_b + 1179648,  589824);
  cvt(Wo, Wo_b, 589824);
  cvt(W1, W1_b, 2359296);
  cvt(W2, W2_b, 2359296);

  gemm_bt<EPI_QKV><<<dim3(2304/128, 8192/128), 256, 0, stream>>>(
      xb, Wqkv_b, 8192, 2304, 768, qkv, nullptr, nullptr, nullptr);

  u16* qb_ = qkv;
  u16* kb_ = qkv + 6291456;
  u16* vb_ = qkv + 12582912;

  transpose_v<<<dim3(32, 48), 256, 0, stream>>>(vb_, vt);

  flash_attn<<<dim3(1536), 256, 0, stream>>>(qb_, kb_, vt, ctxb);

  gemm_bt<EPI_WO><<<dim3(768/128, 8192/128), 256, 0, stream>>>(
      ctxb, Wo_b, 8192, 768, 768, nullptr, resid1, x, nullptr);

  ln_k<0><<<2048, 256, 0, stream>>>(resid1, g1, be1, hb);

  gemm_bt<EPI_FFN1><<<dim3(3072/128, 8192/128), 256, 0, stream>>>(
      hb, W1_b, 8192, 3072, 768, hidden, nullptr, b1, nullptr);

  gemm_bt<EPI_FFN2><<<dim3(768/128, 8192/128), 256, 0, stream>>>(
      hidden, W2_b, 8192, 768, 3072, nullptr, pre2, b2, hb);

  ln_k<1><<<2048, 256, 0, stream>>>(pre2, g2, be2, out);
}

// Round 4
// 355.049 us; speedup vs baseline: 1.6243x; 1.0677x over previous
//
#include <hip/hip_runtime.h>

typedef unsigned short u16;
typedef unsigned int u32;
typedef __attribute__((ext_vector_type(8))) short short8;
typedef __attribute__((ext_vector_type(4))) float f32x4;
typedef __attribute__((ext_vector_type(4))) unsigned short u16x4;

__device__ __forceinline__ float b2f(u16 u){
  union { float f; unsigned int i; } c; c.i = ((unsigned int)u) << 16; return c.f;
}
__device__ __forceinline__ u16 f2b(float f){
  union { float f; unsigned int i; } c; c.f = f;
  unsigned int i = c.i;
  unsigned int r = (i + 0x7FFFu + ((i >> 16) & 1u)) >> 16;
  return (u16)r;
}

#define EXP2(x) exp2f(x)

#define GLD16(gp, lp) __builtin_amdgcn_global_load_lds( \
    (const __attribute__((address_space(1))) void*)(gp), \
    (__attribute__((address_space(3))) void*)(lp), 16, 0, 0)

__device__ __forceinline__ u32 pkbf(float lo, float hi){
  u32 r;
  asm volatile("v_cvt_pk_bf16_f32 %0, %1, %2" : "=v"(r) : "v"(lo), "v"(hi));
  return r;
}

// ---------------------------------------------------------------- fused convert (7 segments, contiguous dst)
__global__ __launch_bounds__(256) void cvt_all(
    const float* __restrict__ s0, const float* __restrict__ s1,
    const float* __restrict__ s2, const float* __restrict__ s3,
    const float* __restrict__ s4, const float* __restrict__ s5,
    const float* __restrict__ s6, u16* __restrict__ dst)
{
  const int i = (blockIdx.x * 256 + threadIdx.x) * 4;
  const float* sp;
  if      (i <  6291456) sp = s0 + i;
  else if (i <  6881280) sp = s1 + (i - 6291456);
  else if (i <  7471104) sp = s2 + (i - 6881280);
  else if (i <  8060928) sp = s3 + (i - 7471104);
  else if (i <  8650752) sp = s4 + (i - 8060928);
  else if (i < 11010048) sp = s5 + (i - 8650752);
  else                   sp = s6 + (i - 11010048);
  float4 f = *(const float4*)sp;
  u16x4 o = { f2b(f.x), f2b(f.y), f2b(f.z), f2b(f.w) };
  *(u16x4*)(dst + i) = o;
}

// ---------------------------------------------------------------- V transpose: [b,h,s,e] -> [b,h,e,s]
__global__ __launch_bounds__(256) void transpose_v(const u16* __restrict__ v,
                                                   u16* __restrict__ vt){
  __shared__ short t[64][72];
  const int plane = blockIdx.y;
  const u16* vp = v + (size_t)plane * 2048 * 64;
  u16* vtp = vt + (size_t)plane * 2048 * 64;
  const int s0 = blockIdx.x * 64;
#pragma unroll
  for (int j = 0; j < 2; j++){
    int ch = threadIdx.x + 256*j;
    int r = ch >> 3, c = (ch & 7) << 3;
    short8 val = *(const short8*)(vp + (size_t)(s0 + r)*64 + c);
#pragma unroll
    for (int jj = 0; jj < 8; jj++) t[c + jj][r] = val[jj];
  }
  __syncthreads();
#pragma unroll
  for (int j = 0; j < 2; j++){
    int ch = threadIdx.x + 256*j;
    int r = ch >> 3, c = (ch & 7) << 3;
    *(short8*)(vtp + (size_t)r*2048 + s0 + c) = *(const short8*)&t[r][c];
  }
}

// ---------------------------------------------------------------- GEMM C = A @ B^T (+epilogue)
enum { EPI_QKV = 0, EPI_WO = 1, EPI_FFN1 = 2, EPI_FFN2 = 3 };

template<int EPI>
__global__ __launch_bounds__(256) void gemm_bt(
    const u16* __restrict__ A, const u16* __restrict__ Bm,
    int M, int N, int K,
    u16* __restrict__ outB, float* __restrict__ outF,
    const float* __restrict__ auxF, const u16* __restrict__ auxB)
{
  __shared__ __align__(16) short Asm[128][32];
  __shared__ __align__(16) short Bsm[128][32];
  const int tid  = threadIdx.x;
  const int lane = tid & 63;
  const int wid  = tid >> 6;
  const int wr = wid >> 1, wc = wid & 1;
  const int fr = lane & 15, fq = lane >> 4;
  const int m0 = blockIdx.y * 128, n0 = blockIdx.x * 128;

  f32x4 acc[4][4];
#pragma unroll
  for (int i = 0; i < 4; i++)
#pragma unroll
    for (int j = 0; j < 4; j++) acc[i][j] = (f32x4){0.f, 0.f, 0.f, 0.f};

  const int lrow = lane >> 2;
  const int lcol = (lane & 3) << 3;

  for (int k0 = 0; k0 < K; k0 += 32) {
    const u16* ga = A  + (size_t)(m0 + wid*32 + lrow) * K + k0 + lcol;
    const u16* gb = Bm + (size_t)(n0 + wid*32 + lrow) * K + k0 + lcol;
    GLD16(ga,                 &Asm[wid*32][0]);
    GLD16(ga + (size_t)16*K,  &Asm[wid*32 + 16][0]);
    GLD16(gb,                 &Bsm[wid*32][0]);
    GLD16(gb + (size_t)16*K,  &Bsm[wid*32 + 16][0]);
    __syncthreads();

    short8 af[4], bf[4];
#pragma unroll
    for (int i = 0; i < 4; i++) af[i] = *(const short8*)&Asm[wr*64 + i*16 + fr][fq*8];
#pragma unroll
    for (int j = 0; j < 4; j++) bf[j] = *(const short8*)&Bsm[wc*64 + j*16 + fr][fq*8];
#pragma unroll
    for (int i = 0; i < 4; i++)
#pragma unroll
      for (int j = 0; j < 4; j++)
        acc[i][j] = __builtin_amdgcn_mfma_f32_16x16x32_bf16(af[i], bf[j], acc[i][j], 0, 0, 0);
    __syncthreads();
  }

  const float KSCALE = 0.125f * 1.44269504088896340736f;
#pragma unroll
  for (int i = 0; i < 4; i++) {
    const int row0 = m0 + wr*64 + i*16 + fq*4;
#pragma unroll
    for (int j = 0; j < 4; j++) {
      const int col = n0 + wc*64 + j*16 + fr;
#pragma unroll
      for (int r = 0; r < 4; r++) {
        const int row = row0 + r;
        float val = acc[i][j][r];
        if (EPI == EPI_QKV) {
          int t = (col >= 1536) ? 2 : (col >= 768 ? 1 : 0);
          int rem = col - t * 768;
          int h = rem >> 6, e = rem & 63;
          int bb = row >> 11, s = row & 2047;
          size_t idx = (((size_t)(t*48 + bb*12 + h)) * 2048 + s) * 64 + e;
          if (t == 1) val *= KSCALE;
          outB[idx] = f2b(val);
        } else if (EPI == EPI_WO) {
          size_t idx = (size_t)row * 768 + col;
          outF[idx] = val + auxF[idx];
        } else if (EPI == EPI_FFN1) {
          float o = val + auxF[col];
          o = o > 0.f ? o : 0.f;
          outB[(size_t)row * 3072 + col] = f2b(o);
        } else {
          size_t idx = (size_t)row * 768 + col;
          outF[idx] = val + auxF[col] + b2f(auxB[idx]);
        }
      }
    }
  }
}

// ---------------------------------------------------------------- flash attention
// Swapped QK^T with K-row-permuted MFMA calls so P lands directly in PV B-frag
// layout (zero cross-lane redistribution). GLD dbuf staging, 1 barrier/iter.
// LDS chunk swizzle f(r)=(r&3)|(((r>>3)&1)<<2) applied to global source & reads.
__global__ __launch_bounds__(256) void flash_attn(
    const u16* __restrict__ q, const u16* __restrict__ kmat, const u16* __restrict__ vtmat,
    u16* __restrict__ ctx)
{
  const int tid = threadIdx.x;
  const int lane = tid & 63, wid = tid >> 6;
  const int fr = lane & 15, fq = lane >> 4;
  const int orig = blockIdx.x;
  const int wg = (orig & 7) * 192 + (orig >> 3);   // bijective XCD swizzle (1536=8*192)
  const int qb = wg & 31;
  const int ph = wg >> 5;
  const size_t plane = (size_t)ph * 2048 * 64;
  const u16* qp  = q + plane;
  const u16* kp  = kmat + plane;
  const u16* vtp = vtmat + plane;

  __shared__ __align__(16) short Ksm[2][64][64];
  __shared__ __align__(16) short Vsm[2][64][64];

  const int qr0 = qb*64 + wid*16;
  const short8 aq0 = *(const short8*)(qp + (size_t)(qr0 + fr)*64 + fq*8);
  const short8 aq1 = *(const short8*)(qp + (size_t)(qr0 + fr)*64 + 32 + fq*8);

  // staging geometry: wave stages rows [wid*16, wid*16+16), 8 rows per GLD
  const int rA = wid*16 + (lane >> 3);
  const int rB = rA + 8;
  const int cA = (((lane & 7) ^ ((rA & 3) | (((rA >> 3) & 1) << 2)))) * 8;
  const int cB = (((lane & 7) ^ ((rB & 3) | (((rB >> 3) & 1) << 2)))) * 8;

#define STAGE(B, KT) do { \
    GLD16(kp  + (size_t)((KT)*64 + rA)*64 + cA,  &Ksm[B][wid*16    ][0]); \
    GLD16(kp  + (size_t)((KT)*64 + rB)*64 + cB,  &Ksm[B][wid*16 + 8][0]); \
    GLD16(vtp + (size_t)rA*2048 + (KT)*64 + cA,  &Vsm[B][wid*16    ][0]); \
    GLD16(vtp + (size_t)rB*2048 + (KT)*64 + cB,  &Vsm[B][wid*16 + 8][0]); \
  } while(0)

  f32x4 o[4];
#pragma unroll
  for (int eb = 0; eb < 4; eb++) o[eb] = (f32x4){0.f, 0.f, 0.f, 0.f};
  float m = -1e30f, l = 0.f;
  const f32x4 zero = (f32x4){0.f, 0.f, 0.f, 0.f};

  STAGE(0, 0);
  __syncthreads();

  // read-side constants
  const int fK  = (fr & 3) | (((fr >> 2) & 1) << 2);   // f(rK), rK=32h+4c+(fr&3)+8(fr>>2)
  const int kc0 = ((fq    ) ^ fK) * 8;
  const int kc1 = ((4 + fq) ^ fK) * 8;
  const int krow = (fr & 3) + 8 * (fr >> 2);
  const int fV  = (fr & 3) | (((fr >> 3) & 1) << 2);   // f(rV), rV=eb*16+fr
  const int vc0 = ((fq    ) ^ fV) * 8;
  const int vc1 = ((4 + fq) ^ fV) * 8;

  int buf = 0;
  for (int kt = 0; kt < 32; ++kt) {
    if (kt < 31) STAGE(buf ^ 1, kt + 1);

    // S^T via K-row-permuted calls: call (h,c) -> lane gets kk = 32h+8fq+4c+r
    f32x4 st[2][2];
    __builtin_amdgcn_s_setprio(1);
#pragma unroll
    for (int h = 0; h < 2; h++)
#pragma unroll
      for (int c = 0; c < 2; c++) {
        const short* kr = &Ksm[buf][32*h + 4*c + krow][0];
        short8 kf0 = *(const short8*)(kr + kc0);
        short8 kf1 = *(const short8*)(kr + kc1);
        f32x4 a = __builtin_amdgcn_mfma_f32_16x16x32_bf16(kf0, aq0, zero, 0, 0, 0);
        st[h][c]  = __builtin_amdgcn_mfma_f32_16x16x32_bf16(kf1, aq1, a,    0, 0, 0);
      }
    __builtin_amdgcn_s_setprio(0);

    float lm = st[0][0][0];
#pragma unroll
    for (int h = 0; h < 2; h++)
#pragma unroll
      for (int c = 0; c < 2; c++)
#pragma unroll
        for (int r = 0; r < 4; r++) lm = fmaxf(lm, st[h][c][r]);
    lm = fmaxf(lm, __shfl_xor(lm, 16));
    lm = fmaxf(lm, __shfl_xor(lm, 32));

    if (!__all(lm <= m + 8.f)) {          // defer-max, THR=8 (log2 units)
      float nm = fmaxf(m, lm);
      float corr = EXP2(m - nm);
      m = nm;
      l *= corr;
#pragma unroll
      for (int eb = 0; eb < 4; eb++)
#pragma unroll
        for (int r = 0; r < 4; r++) o[eb][r] *= corr;
    }

    float p[2][2][4];
    float ls = 0.f;
#pragma unroll
    for (int h = 0; h < 2; h++)
#pragma unroll
      for (int c = 0; c < 2; c++)
#pragma unroll
        for (int r = 0; r < 4; r++) {
          float pv = EXP2(st[h][c][r] - m);
          p[h][c][r] = pv;
          ls += pv;
        }
    ls += __shfl_xor(ls, 16);
    ls += __shfl_xor(ls, 32);
    l += ls;

    union { u32 u[4]; short8 s8; } pf0, pf1;
    pf0.u[0] = pkbf(p[0][0][0], p[0][0][1]);
    pf0.u[1] = pkbf(p[0][0][2], p[0][0][3]);
    pf0.u[2] = pkbf(p[0][1][0], p[0][1][1]);
    pf0.u[3] = pkbf(p[0][1][2], p[0][1][3]);
    pf1.u[0] = pkbf(p[1][0][0], p[1][0][1]);
    pf1.u[1] = pkbf(p[1][0][2], p[1][0][3]);
    pf1.u[2] = pkbf(p[1][1][0], p[1][1][1]);
    pf1.u[3] = pkbf(p[1][1][2], p[1][1][3]);

    __builtin_amdgcn_s_setprio(1);
#pragma unroll
    for (int eb = 0; eb < 4; eb++) {
      const short* vr = &Vsm[buf][eb*16 + fr][0];
      o[eb] = __builtin_amdgcn_mfma_f32_16x16x32_bf16(*(const short8*)(vr + vc0), pf0.s8, o[eb], 0, 0, 0);
      o[eb] = __builtin_amdgcn_mfma_f32_16x16x32_bf16(*(const short8*)(vr + vc1), pf1.s8, o[eb], 0, 0, 0);
    }
    __builtin_amdgcn_s_setprio(0);

    __syncthreads();                       // drains own vmcnt (next tile landed)
    buf ^= 1;
  }
#undef STAGE

  const float inv = 1.0f / l;
  const int s = qr0 + fr;
  u16* cp = ctx + ((size_t)((ph/12)*2048 + s)) * 768 + (ph%12)*64;
#pragma unroll
  for (int eb = 0; eb < 4; eb++) {
    u16x4 w = { f2b(o[eb][0]*inv), f2b(o[eb][1]*inv), f2b(o[eb][2]*inv), f2b(o[eb][3]*inv) };
    *(u16x4*)(cp + eb*16 + fq*4) = w;
  }
}

// ---------------------------------------------------------------- layernorm (wave per row)
template<int F32OUT>
__global__ __launch_bounds__(256) void ln_k(const float* __restrict__ in,
    const float* __restrict__ g, const float* __restrict__ be, void* __restrict__ outp)
{
  const int lane = threadIdx.x & 63, wid = threadIdx.x >> 6;
  const int row = blockIdx.x * 4 + wid;
  const float* p = in + (size_t)row * 768;
  float v[12];
  float s = 0.f, s2 = 0.f;
#pragma unroll
  for (int i = 0; i < 12; i++) { v[i] = p[lane + 64*i]; s += v[i]; s2 += v[i]*v[i]; }
#pragma unroll
  for (int msk = 1; msk < 64; msk <<= 1) { s += __shfl_xor(s, msk); s2 += __shfl_xor(s2, msk); }
  const float mu = s * (1.f/768.f);
  const float var = s2 * (1.f/768.f) - mu*mu;
  const float rstd = rsqrtf(var + 1e-5f);
#pragma unroll
  for (int i = 0; i < 12; i++) {
    int c = lane + 64*i;
    float o = (v[i] - mu) * rstd * g[c] + be[c];
    if (F32OUT) ((float*)outp)[(size_t)row*768 + c] = o;
    else        ((u16*)outp)[(size_t)row*768 + c] = f2b(o);
  }
}

// ---------------------------------------------------------------- launch
extern "C" void kernel_launch(void* const* d_in, const int* in_sizes, int n_in,
                              void* d_out, int out_size, void* d_ws, size_t ws_size,
                              hipStream_t stream)
{
  const float* x   = (const float*)d_in[0];
  const float* Wq  = (const float*)d_in[1];
  const float* Wk  = (const float*)d_in[2];
  const float* Wv  = (const float*)d_in[3];
  const float* Wo  = (const float*)d_in[4];
  const float* W1  = (const float*)d_in[5];
  const float* b1  = (const float*)d_in[6];
  const float* W2  = (const float*)d_in[7];
  const float* b2  = (const float*)d_in[8];
  const float* g1  = (const float*)d_in[9];
  const float* be1 = (const float*)d_in[10];
  const float* g2  = (const float*)d_in[11];
  const float* be2 = (const float*)d_in[12];
  float* out = (float*)d_out;

  char* ws = (char*)d_ws;
  u16* xb     = (u16*)(ws + 0);
  u16* Wqkv_b = (u16*)(ws + 12582912);
  u16* Wo_b   = (u16*)(ws + 16121856);
  u16* W1_b   = (u16*)(ws + 17301504);
  u16* W2_b   = (u16*)(ws + 22020096);
  u16* qkv    = (u16*)(ws + 26738688);
  u16* ctxb   = (u16*)(ws + 64487424);
  u16* hidden = (u16*)(ws + 26738688);     // alias qkv+ctx
  float* resid1 = (float*)(ws + 77070336);
  u16* vt     = (u16*)(ws + 77070336);     // aliases resid1 (dead until WO gemm)
  u16* hb     = (u16*)(ws + 102236160);
  float* pre2 = (float*)(ws + 77070336);

  // one fused f32->bf16 convert for x + all weights (dsts contiguous at ws+0)
  cvt_all<<<dim3(13056), 256, 0, stream>>>(x, Wq, Wk, Wv, Wo, W1, W2, (u16*)ws);

  gemm_bt<EPI_QKV><<<dim3(2304/128, 8192/128), 256, 0, stream>>>(
      xb, Wqkv_b, 8192, 2304, 768, qkv, nullptr, nullptr, nullptr);

  u16* qb_ = qkv;
  u16* kb_ = qkv + 6291456;
  u16* vb_ = qkv + 12582912;

  transpose_v<<<dim3(32, 48), 256, 0, stream>>>(vb_, vt);

  flash_attn<<<dim3(1536), 256, 0, stream>>>(qb_, kb_, vt, ctxb);

  gemm_bt<EPI_WO><<<dim3(768/128, 8192/128), 256, 0, stream>>>(
      ctxb, Wo_b, 8192, 768, 768, nullptr, resid1, x, nullptr);

  ln_k<0><<<2048, 256, 0, stream>>>(resid1, g1, be1, hb);

  gemm_bt<EPI_FFN1><<<dim3(3072/128, 8192/128), 256, 0, stream>>>(
      hb, W1_b, 8192, 3072, 768, hidden, nullptr, b1, nullptr);

  gemm_bt<EPI_FFN2><<<dim3(768/128, 8192/128), 256, 0, stream>>>(
      hidden, W2_b, 8192, 768, 3072, nullptr, pre2, b2, hb);

  ln_k<1><<<2048, 256, 0, stream>>>(pre2, g2, be2, out);
}

// Round 5
// 354.560 us; speedup vs baseline: 1.6266x; 1.0014x over previous
//
#include <hip/hip_runtime.h>

typedef unsigned short u16;
typedef unsigned int u32;
typedef __attribute__((ext_vector_type(8))) short short8;
typedef __attribute__((ext_vector_type(4))) float f32x4;
typedef __attribute__((ext_vector_type(4))) unsigned short u16x4;

__device__ __forceinline__ float b2f(u16 u){
  union { float f; unsigned int i; } c; c.i = ((unsigned int)u) << 16; return c.f;
}
__device__ __forceinline__ u16 f2b(float f){
  union { float f; unsigned int i; } c; c.f = f;
  unsigned int i = c.i;
  unsigned int r = (i + 0x7FFFu + ((i >> 16) & 1u)) >> 16;
  return (u16)r;
}

#define EXP2(x) exp2f(x)

#define GLD16(gp, lp) __builtin_amdgcn_global_load_lds( \
    (const __attribute__((address_space(1))) void*)(gp), \
    (__attribute__((address_space(3))) void*)(lp), 16, 0, 0)

__device__ __forceinline__ u32 pkbf(float lo, float hi){
  u32 r;
  asm volatile("v_cvt_pk_bf16_f32 %0, %1, %2" : "=v"(r) : "v"(lo), "v"(hi));
  return r;
}

// ---------------------------------------------------------------- fused convert (7 segments, contiguous dst)
__global__ __launch_bounds__(256) void cvt_all(
    const float* __restrict__ s0, const float* __restrict__ s1,
    const float* __restrict__ s2, const float* __restrict__ s3,
    const float* __restrict__ s4, const float* __restrict__ s5,
    const float* __restrict__ s6, u16* __restrict__ dst)
{
  const int i = (blockIdx.x * 256 + threadIdx.x) * 4;
  const float* sp;
  if      (i <  6291456) sp = s0 + i;
  else if (i <  6881280) sp = s1 + (i - 6291456);
  else if (i <  7471104) sp = s2 + (i - 6881280);
  else if (i <  8060928) sp = s3 + (i - 7471104);
  else if (i <  8650752) sp = s4 + (i - 8060928);
  else if (i < 11010048) sp = s5 + (i - 8650752);
  else                   sp = s6 + (i - 11010048);
  float4 f = *(const float4*)sp;
  u16x4 o = { f2b(f.x), f2b(f.y), f2b(f.z), f2b(f.w) };
  *(u16x4*)(dst + i) = o;
}

// ---------------------------------------------------------------- V transpose: [b,h,s,e] -> [b,h,e,s]
__global__ __launch_bounds__(256) void transpose_v(const u16* __restrict__ v,
                                                   u16* __restrict__ vt){
  __shared__ short t[64][72];
  const int plane = blockIdx.y;
  const u16* vp = v + (size_t)plane * 2048 * 64;
  u16* vtp = vt + (size_t)plane * 2048 * 64;
  const int s0 = blockIdx.x * 64;
#pragma unroll
  for (int j = 0; j < 2; j++){
    int ch = threadIdx.x + 256*j;
    int r = ch >> 3, c = (ch & 7) << 3;
    short8 val = *(const short8*)(vp + (size_t)(s0 + r)*64 + c);
#pragma unroll
    for (int jj = 0; jj < 8; jj++) t[c + jj][r] = val[jj];
  }
  __syncthreads();
#pragma unroll
  for (int j = 0; j < 2; j++){
    int ch = threadIdx.x + 256*j;
    int r = ch >> 3, c = (ch & 7) << 3;
    *(short8*)(vtp + (size_t)r*2048 + s0 + c) = *(const short8*)&t[r][c];
  }
}

// ---------------------------------------------------------------- GEMM C = A @ B^T (+epilogue), BK=64
enum { EPI_QKV = 0, EPI_WO = 1, EPI_FFN1 = 2, EPI_FFN2 = 3 };

template<int EPI>
__global__ __launch_bounds__(256) void gemm_bt(
    const u16* __restrict__ A, const u16* __restrict__ Bm,
    int M, int N, int K,
    u16* __restrict__ outB,
    const float* __restrict__ auxF,  // FFN1: b1; FFN2: b2
    const u16* __restrict__ auxB)    // WO: xb (residual); FFN2: hb (residual)
{
  __shared__ __align__(16) short Asm[128][64];
  __shared__ __align__(16) short Bsm[128][64];
  const int tid  = threadIdx.x;
  const int lane = tid & 63;
  const int wid  = tid >> 6;
  const int wr = wid >> 1, wc = wid & 1;
  const int fr = lane & 15, fq = lane >> 4;
  const int m0 = blockIdx.y * 128, n0 = blockIdx.x * 128;

  f32x4 acc[4][4];
#pragma unroll
  for (int i = 0; i < 4; i++)
#pragma unroll
    for (int j = 0; j < 4; j++) acc[i][j] = (f32x4){0.f, 0.f, 0.f, 0.f};

  const int srow = lane >> 3;          // 0..7
  const int scol = (lane & 7) << 3;    // 0..56 shorts

  for (int k0 = 0; k0 < K; k0 += 64) {
    const u16* ga = A  + (size_t)(m0 + wid*32 + srow) * K + k0 + scol;
    const u16* gb = Bm + (size_t)(n0 + wid*32 + srow) * K + k0 + scol;
#pragma unroll
    for (int o = 0; o < 4; o++) {
      GLD16(ga + (size_t)(o*8)*K, &Asm[wid*32 + o*8][0]);
      GLD16(gb + (size_t)(o*8)*K, &Bsm[wid*32 + o*8][0]);
    }
    __syncthreads();

    short8 a[4], b[4];
#pragma unroll
    for (int i = 0; i < 4; i++) a[i] = *(const short8*)&Asm[wr*64 + i*16 + fr][fq*8];
#pragma unroll
    for (int j = 0; j < 4; j++) b[j] = *(const short8*)&Bsm[wc*64 + j*16 + fr][fq*8];
#pragma unroll
    for (int i = 0; i < 4; i++)
#pragma unroll
      for (int j = 0; j < 4; j++)
        acc[i][j] = __builtin_amdgcn_mfma_f32_16x16x32_bf16(a[i], b[j], acc[i][j], 0, 0, 0);
#pragma unroll
    for (int i = 0; i < 4; i++) a[i] = *(const short8*)&Asm[wr*64 + i*16 + fr][32 + fq*8];
#pragma unroll
    for (int j = 0; j < 4; j++) b[j] = *(const short8*)&Bsm[wc*64 + j*16 + fr][32 + fq*8];
#pragma unroll
    for (int i = 0; i < 4; i++)
#pragma unroll
      for (int j = 0; j < 4; j++)
        acc[i][j] = __builtin_amdgcn_mfma_f32_16x16x32_bf16(a[i], b[j], acc[i][j], 0, 0, 0);
    __syncthreads();
  }

  const float KSCALE = 0.125f * 1.44269504088896340736f;
#pragma unroll
  for (int i = 0; i < 4; i++) {
    const int row0 = m0 + wr*64 + i*16 + fq*4;
#pragma unroll
    for (int j = 0; j < 4; j++) {
      const int col = n0 + wc*64 + j*16 + fr;
#pragma unroll
      for (int r = 0; r < 4; r++) {
        const int row = row0 + r;
        float val = acc[i][j][r];
        if (EPI == EPI_QKV) {
          int t = (col >= 1536) ? 2 : (col >= 768 ? 1 : 0);
          int rem = col - t * 768;
          int h = rem >> 6, e = rem & 63;
          int bb = row >> 11, s = row & 2047;
          size_t idx = (((size_t)(t*48 + bb*12 + h)) * 2048 + s) * 64 + e;
          if (t == 1) val *= KSCALE;
          outB[idx] = f2b(val);
        } else if (EPI == EPI_WO) {
          size_t idx = (size_t)row * 768 + col;
          outB[idx] = f2b(val + b2f(auxB[idx]));
        } else if (EPI == EPI_FFN1) {
          float o = val + auxF[col];
          o = o > 0.f ? o : 0.f;
          outB[(size_t)row * 3072 + col] = f2b(o);
        } else {
          size_t idx = (size_t)row * 768 + col;
          outB[idx] = f2b(val + auxF[col] + b2f(auxB[idx]));
        }
      }
    }
  }
}

// ---------------------------------------------------------------- flash attention
// Swapped QK^T, K-row-permuted MFMA (P lands in PV B-frag layout, zero shuffles),
// GLD dbuf staging 1 barrier/iter, both-sides LDS swizzle, l via ones-MFMA.
__global__ __launch_bounds__(256) void flash_attn(
    const u16* __restrict__ q, const u16* __restrict__ kmat, const u16* __restrict__ vtmat,
    u16* __restrict__ ctx)
{
  const int tid = threadIdx.x;
  const int lane = tid & 63, wid = tid >> 6;
  const int fr = lane & 15, fq = lane >> 4;
  const int orig = blockIdx.x;
  const int wg = (orig & 7) * 192 + (orig >> 3);   // bijective XCD swizzle (1536=8*192)
  const int qb = wg & 31;
  const int ph = wg >> 5;
  const size_t plane = (size_t)ph * 2048 * 64;
  const u16* qp  = q + plane;
  const u16* kp  = kmat + plane;
  const u16* vtp = vtmat + plane;

  __shared__ __align__(16) short Ksm[2][64][64];
  __shared__ __align__(16) short Vsm[2][64][64];

  const int qr0 = qb*64 + wid*16;
  const short8 aq0 = *(const short8*)(qp + (size_t)(qr0 + fr)*64 + fq*8);
  const short8 aq1 = *(const short8*)(qp + (size_t)(qr0 + fr)*64 + 32 + fq*8);

  short8 vones;
#pragma unroll
  for (int j = 0; j < 8; j++) vones[j] = (short)0x3F80;   // bf16 1.0

  const int rA = wid*16 + (lane >> 3);
  const int rB = rA + 8;
  const int cA = (((lane & 7) ^ ((rA & 3) | (((rA >> 3) & 1) << 2)))) * 8;
  const int cB = (((lane & 7) ^ ((rB & 3) | (((rB >> 3) & 1) << 2)))) * 8;

#define STAGE(B, KT) do { \
    GLD16(kp  + (size_t)((KT)*64 + rA)*64 + cA,  &Ksm[B][wid*16    ][0]); \
    GLD16(kp  + (size_t)((KT)*64 + rB)*64 + cB,  &Ksm[B][wid*16 + 8][0]); \
    GLD16(vtp + (size_t)rA*2048 + (KT)*64 + cA,  &Vsm[B][wid*16    ][0]); \
    GLD16(vtp + (size_t)rB*2048 + (KT)*64 + cB,  &Vsm[B][wid*16 + 8][0]); \
  } while(0)

  f32x4 o[4];
#pragma unroll
  for (int eb = 0; eb < 4; eb++) o[eb] = (f32x4){0.f, 0.f, 0.f, 0.f};
  float m = -1e30f, l = 0.f;
  const f32x4 zero = (f32x4){0.f, 0.f, 0.f, 0.f};

  STAGE(0, 0);
  __syncthreads();

  const int fK  = (fr & 3) | (((fr >> 2) & 1) << 2);
  const int kc0 = ((fq    ) ^ fK) * 8;
  const int kc1 = ((4 + fq) ^ fK) * 8;
  const int krow = (fr & 3) + 8 * (fr >> 2);
  const int fV  = (fr & 3) | (((fr >> 3) & 1) << 2);
  const int vc0 = ((fq    ) ^ fV) * 8;
  const int vc1 = ((4 + fq) ^ fV) * 8;

  int buf = 0;
  for (int kt = 0; kt < 32; ++kt) {
    if (kt < 31) STAGE(buf ^ 1, kt + 1);

    f32x4 st[2][2];
    __builtin_amdgcn_s_setprio(1);
#pragma unroll
    for (int h = 0; h < 2; h++)
#pragma unroll
      for (int c = 0; c < 2; c++) {
        const short* kr = &Ksm[buf][32*h + 4*c + krow][0];
        short8 kf0 = *(const short8*)(kr + kc0);
        short8 kf1 = *(const short8*)(kr + kc1);
        f32x4 a = __builtin_amdgcn_mfma_f32_16x16x32_bf16(kf0, aq0, zero, 0, 0, 0);
        st[h][c]  = __builtin_amdgcn_mfma_f32_16x16x32_bf16(kf1, aq1, a,    0, 0, 0);
      }
    __builtin_amdgcn_s_setprio(0);

    // max tree (max3-fusable nesting)
    float t0 = fmaxf(fmaxf(st[0][0][0], st[0][0][1]), st[0][0][2]);
    float t1 = fmaxf(fmaxf(st[0][0][3], st[0][1][0]), st[0][1][1]);
    float t2 = fmaxf(fmaxf(st[0][1][2], st[0][1][3]), st[1][0][0]);
    float t3 = fmaxf(fmaxf(st[1][0][1], st[1][0][2]), st[1][0][3]);
    float t4 = fmaxf(fmaxf(st[1][1][0], st[1][1][1]), st[1][1][2]);
    float u0 = fmaxf(fmaxf(t0, t1), st[1][1][3]);
    float u1 = fmaxf(fmaxf(t2, t3), t4);
    float lm = fmaxf(u0, u1);
    lm = fmaxf(lm, __shfl_xor(lm, 16));
    lm = fmaxf(lm, __shfl_xor(lm, 32));

    if (!__all(lm <= m + 8.f)) {          // defer-max, THR=8 (log2 units)
      float nm = fmaxf(m, lm);
      float corr = EXP2(m - nm);
      m = nm;
      l *= corr;
#pragma unroll
      for (int eb = 0; eb < 4; eb++)
#pragma unroll
        for (int r = 0; r < 4; r++) o[eb][r] *= corr;
    }

    float p[2][2][4];
#pragma unroll
    for (int h = 0; h < 2; h++)
#pragma unroll
      for (int c = 0; c < 2; c++)
#pragma unroll
        for (int r = 0; r < 4; r++)
          p[h][c][r] = EXP2(st[h][c][r] - m);

    union { u32 u[4]; short8 s8; } pf0, pf1;
    pf0.u[0] = pkbf(p[0][0][0], p[0][0][1]);
    pf0.u[1] = pkbf(p[0][0][2], p[0][0][3]);
    pf0.u[2] = pkbf(p[0][1][0], p[0][1][1]);
    pf0.u[3] = pkbf(p[0][1][2], p[0][1][3]);
    pf1.u[0] = pkbf(p[1][0][0], p[1][0][1]);
    pf1.u[1] = pkbf(p[1][0][2], p[1][0][3]);
    pf1.u[2] = pkbf(p[1][1][0], p[1][1][1]);
    pf1.u[3] = pkbf(p[1][1][2], p[1][1][3]);

    __builtin_amdgcn_s_setprio(1);
    // l = sum_k P[k][q] via ones-row MFMA (all regs equal l[q=fr])
    f32x4 ol = __builtin_amdgcn_mfma_f32_16x16x32_bf16(vones, pf0.s8, zero, 0, 0, 0);
    ol       = __builtin_amdgcn_mfma_f32_16x16x32_bf16(vones, pf1.s8, ol,   0, 0, 0);
#pragma unroll
    for (int eb = 0; eb < 4; eb++) {
      const short* vr = &Vsm[buf][eb*16 + fr][0];
      o[eb] = __builtin_amdgcn_mfma_f32_16x16x32_bf16(*(const short8*)(vr + vc0), pf0.s8, o[eb], 0, 0, 0);
      o[eb] = __builtin_amdgcn_mfma_f32_16x16x32_bf16(*(const short8*)(vr + vc1), pf1.s8, o[eb], 0, 0, 0);
    }
    __builtin_amdgcn_s_setprio(0);
    l += ol[0];

    __syncthreads();
    buf ^= 1;
  }
#undef STAGE

  const float inv = 1.0f / l;
  const int s = qr0 + fr;
  u16* cp = ctx + ((size_t)((ph/12)*2048 + s)) * 768 + (ph%12)*64;
#pragma unroll
  for (int eb = 0; eb < 4; eb++) {
    u16x4 w = { f2b(o[eb][0]*inv), f2b(o[eb][1]*inv), f2b(o[eb][2]*inv), f2b(o[eb][3]*inv) };
    *(u16x4*)(cp + eb*16 + fq*4) = w;
  }
}

// ---------------------------------------------------------------- layernorm (wave per row, bf16 in)
template<int F32OUT>
__global__ __launch_bounds__(256) void ln_k(const u16* __restrict__ in,
    const float* __restrict__ g, const float* __restrict__ be, void* __restrict__ outp)
{
  const int lane = threadIdx.x & 63, wid = threadIdx.x >> 6;
  const int row = blockIdx.x * 4 + wid;
  const u16* p = in + (size_t)row * 768;
  float v[12];
  float s = 0.f, s2 = 0.f;
#pragma unroll
  for (int i = 0; i < 6; i++) {
    ushort2 uv = *(const ushort2*)(p + i*128 + lane*2);
    v[2*i]   = b2f(uv.x);
    v[2*i+1] = b2f(uv.y);
    s += v[2*i] + v[2*i+1];
    s2 += v[2*i]*v[2*i] + v[2*i+1]*v[2*i+1];
  }
#pragma unroll
  for (int msk = 1; msk < 64; msk <<= 1) { s += __shfl_xor(s, msk); s2 += __shfl_xor(s2, msk); }
  const float mu = s * (1.f/768.f);
  const float var = s2 * (1.f/768.f) - mu*mu;
  const float rstd = rsqrtf(var + 1e-5f);
#pragma unroll
  for (int i = 0; i < 6; i++) {
    int c = i*128 + lane*2;
    float o0 = (v[2*i]   - mu) * rstd * g[c]   + be[c];
    float o1 = (v[2*i+1] - mu) * rstd * g[c+1] + be[c+1];
    if (F32OUT) {
      float2 w = { o0, o1 };
      *(float2*)((float*)outp + (size_t)row*768 + c) = w;
    } else {
      ushort2 w = { f2b(o0), f2b(o1) };
      *(ushort2*)((u16*)outp + (size_t)row*768 + c) = w;
    }
  }
}

// ---------------------------------------------------------------- launch
extern "C" void kernel_launch(void* const* d_in, const int* in_sizes, int n_in,
                              void* d_out, int out_size, void* d_ws, size_t ws_size,
                              hipStream_t stream)
{
  const float* x   = (const float*)d_in[0];
  const float* Wq  = (const float*)d_in[1];
  const float* Wk  = (const float*)d_in[2];
  const float* Wv  = (const float*)d_in[3];
  const float* Wo  = (const float*)d_in[4];
  const float* W1  = (const float*)d_in[5];
  const float* b1  = (const float*)d_in[6];
  const float* W2  = (const float*)d_in[7];
  const float* b2  = (const float*)d_in[8];
  const float* g1  = (const float*)d_in[9];
  const float* be1 = (const float*)d_in[10];
  const float* g2  = (const float*)d_in[11];
  const float* be2 = (const float*)d_in[12];
  float* out = (float*)d_out;

  char* ws = (char*)d_ws;
  u16* xb     = (u16*)(ws + 0);
  u16* Wqkv_b = (u16*)(ws + 12582912);
  u16* Wo_b   = (u16*)(ws + 16121856);
  u16* W1_b   = (u16*)(ws + 17301504);
  u16* W2_b   = (u16*)(ws + 22020096);
  u16* qkv    = (u16*)(ws + 26738688);
  u16* ctxb   = (u16*)(ws + 64487424);
  u16* hidden = (u16*)(ws + 26738688);     // alias qkv+ctx
  u16* vt     = (u16*)(ws + 77070336);     // V^T (dead after flash)
  u16* resid1 = (u16*)(ws + 77070336);     // alias vt (bf16 now)
  u16* hb     = (u16*)(ws + 102236160);
  u16* pre2   = (u16*)(ws + 77070336);     // alias resid1

  cvt_all<<<dim3(13056), 256, 0, stream>>>(x, Wq, Wk, Wv, Wo, W1, W2, (u16*)ws);

  gemm_bt<EPI_QKV><<<dim3(2304/128, 8192/128), 256, 0, stream>>>(
      xb, Wqkv_b, 8192, 2304, 768, qkv, nullptr, nullptr);

  u16* qb_ = qkv;
  u16* kb_ = qkv + 6291456;
  u16* vb_ = qkv + 12582912;

  transpose_v<<<dim3(32, 48), 256, 0, stream>>>(vb_, vt);

  flash_attn<<<dim3(1536), 256, 0, stream>>>(qb_, kb_, vt, ctxb);

  gemm_bt<EPI_WO><<<dim3(768/128, 8192/128), 256, 0, stream>>>(
      ctxb, Wo_b, 8192, 768, 768, resid1, nullptr, xb);

  ln_k<0><<<2048, 256, 0, stream>>>(resid1, g1, be1, hb);

  gemm_bt<EPI_FFN1><<<dim3(3072/128, 8192/128), 256, 0, stream>>>(
      hb, W1_b, 8192, 3072, 768, hidden, b1, nullptr);

  gemm_bt<EPI_FFN2><<<dim3(768/128, 8192/128), 256, 0, stream>>>(
      hidden, W2_b, 8192, 768, 3072, pre2, b2, hb);

  ln_k<1><<<2048, 256, 0, stream>>>(pre2, g2, be2, out);
}